// Round 10
// baseline (230.326 us; speedup 1.0000x reference)
//
#include <hip/hip_runtime.h>
#include <hip/hip_bf16.h>
#include <cstdint>
#include <cstddef>

#define SCALE 0.42044820762685725f  // 32^(-1/4)

typedef __attribute__((ext_vector_type(8))) short short8;
typedef __attribute__((ext_vector_type(4))) short short4v;
typedef __attribute__((ext_vector_type(4))) float f32x4;

__device__ __forceinline__ unsigned int pk2bf(float lo, float hi) {
    __hip_bfloat162 h = __float22bfloat162_rn(float2{lo, hi});  // v_cvt_pk_bf16_f32
    unsigned int u;
    __builtin_memcpy(&u, &h, sizeof(u));
    return u;
}
__device__ __forceinline__ unsigned short f2bf(float f) {
    unsigned int u = __builtin_bit_cast(unsigned int, f);
    u = (u + 0x7fffu + ((u >> 16) & 1u)) >> 16;   // RNE
    return (unsigned short)u;
}
__device__ __forceinline__ float bf2f(unsigned short h) {
    unsigned int u = ((unsigned int)h) << 16;
    return __builtin_bit_cast(float, u);
}

// ---------------- ws layout ----------------
// [0,      393216) : W A-frags bf16 (mtg 0..15 K rows 256+16m; 16..31 V rows 512+16m; 32..47 Q rows m*16 — Q frags used only by !PRE fallback)
// [393216, 425984) : posT bf16 [k=64][m=256]
// [425984, 688128) : WqT fp32 [c=256][o=256]
// [688128, 2785280): q_all fp32 [tile=2048][o=256] = scale*(Wq@X0 + bq)

__global__ __launch_bounds__(256) void prepack_w(const float* __restrict__ w,
                                                 const float* __restrict__ pos,
                                                 unsigned short* __restrict__ wp,
                                                 unsigned short* __restrict__ pT,
                                                 float* __restrict__ wqT) {
    int gid = blockIdx.x * 256 + threadIdx.x;    // < 106496
    if (gid < 24576) {
        int lane = gid & 63;
        int ks   = (gid >> 6) & 7;
        int mtg  = gid >> 9;                     // 0..47
        int row  = (mtg < 32 ? 256 + mtg * 16 : (mtg - 32) * 16) + (lane & 15);
        int k0   = ks * 32 + (lane >> 4) * 8;
        const float* src = w + row * 256 + k0;
        short8 v;
#pragma unroll
        for (int j = 0; j < 8; ++j) v[j] = (short)f2bf(src[j]);
        *reinterpret_cast<short8*>(wp + (size_t)gid * 8) = v;
    } else if (gid < 40960) {
        int u = gid - 24576;                     // k*256 + m
        pT[u] = f2bf(pos[(u & 255) * 64 + (u >> 8)]);
    } else {
        int u = gid - 40960;                     // c*256 + o, < 65536
        wqT[u] = w[(u & 255) * 256 + (u >> 8)];
    }
}

// ---------------- q kernel: q_all[tile][o] = scale*(Wq[o]·x[:,p0(tile)] + bq[o]) ----------------
__global__ __launch_bounds__(256) void q_kernel(const float* __restrict__ x,
                                                const float* __restrict__ wqT,
                                                const float* __restrict__ proj_b,
                                                float* __restrict__ q_all) {
    __shared__ float s_x0[4][256];
    const int t = threadIdx.x;
    const int tile0 = blockIdx.x * 4;            // 4 tiles share (b,hq)
    const int b = tile0 >> 8, hq = (tile0 >> 4) & 15, wq0 = tile0 & 15;
    {
        const float* src = x + (size_t)b * 4194304 + (size_t)t * 16384 + hq * 1024 + wq0 * 8;
#pragma unroll
        for (int j = 0; j < 4; ++j) s_x0[j][t] = src[j * 8];
    }
    __syncthreads();
    float acc[4] = {0.f, 0.f, 0.f, 0.f};
#pragma unroll 8
    for (int c = 0; c < 256; ++c) {
        float wv = wqT[c * 256 + t];             // coalesced; LDS reads broadcast
#pragma unroll
        for (int j = 0; j < 4; ++j) acc[j] = fmaf(wv, s_x0[j][c], acc[j]);
    }
    float bq = proj_b[t];
#pragma unroll
    for (int j = 0; j < 4; ++j)
        q_all[(size_t)(tile0 + j) * 256 + t] = SCALE * (acc[j] + bq);
}

// ---------------- main fused kernel: 256 WGs x 8 wq-consecutive tiles, 512 threads ----------------
// Wave w = head w. W (K+V) STATIONARY in 128 VGPRs, loaded once per WG.
// Per tile: pure LDS+MFMA GEMM -> in-register attention; double-buffered x-LDS,
// staging for t+1 issued after GEMM t (T14 split); ONE barrier per tile.
template <bool PRE>
__global__ __launch_bounds__(512, 2) void attn_fused(
        const float* __restrict__ x, const float* __restrict__ proj_w,
        const float* __restrict__ proj_b, const float* __restrict__ pos,
        const unsigned short* __restrict__ wpack, const unsigned short* __restrict__ posT,
        const float* __restrict__ q_all, float* __restrict__ out) {
    __shared__ __align__(16) unsigned char s_x[2][32768];  // x-tile bf16 [p=64][c=256] swizzled
    __shared__ __align__(16) float s_vbias[256];
    __shared__ __align__(16) float s_qs[256];              // !PRE only

    const int t    = threadIdx.x;
    const int lane = t & 63;
    const int wave = t >> 6;          // head id
    const int l15  = lane & 15;
    const int l4   = lane >> 4;

    // XCD-chunked: WG i -> XCD i%8 -> image b=i%8; 8 wq-consecutive tiles share x lines
    const int bid   = blockIdx.x;                  // < 256
    const int tile0 = (bid & 7) * 256 + (bid >> 3) * 8;
    const int b   = tile0 >> 8;
    const int hq  = (tile0 >> 4) & 15;
    const int wq0 = tile0 & 15;                    // 0 or 8

    if (t < 256) s_vbias[t] = proj_b[512 + t];

    // ---- W stationary: K rows 256+32w.., V rows 512+32w.. ; 128 VGPRs, loaded once ----
    short8 wK[2][8], wV[2][8];
    if (PRE) {
#pragma unroll
        for (int mt = 0; mt < 2; ++mt)
#pragma unroll
            for (int ks = 0; ks < 8; ++ks) {
                wK[mt][ks] = *reinterpret_cast<const short8*>(
                    wpack + ((size_t)(((wave * 2 + mt) * 8 + ks) * 64 + lane)) * 8);
                wV[mt][ks] = *reinterpret_cast<const short8*>(
                    wpack + ((size_t)(((16 + wave * 2 + mt) * 8 + ks) * 64 + lane)) * 8);
            }
    } else {
#pragma unroll
        for (int mt = 0; mt < 2; ++mt)
#pragma unroll
            for (int ks = 0; ks < 8; ++ks) {
                const float* wk = proj_w + (256 + (wave * 2 + mt) * 16 + l15) * 256 + ks * 32 + l4 * 8;
                const float* wv = proj_w + (512 + (wave * 2 + mt) * 16 + l15) * 256 + ks * 32 + l4 * 8;
#pragma unroll
                for (int j = 0; j < 8; ++j) {
                    wK[mt][ks][j] = (short)f2bf(wk[j]);
                    wV[mt][ks][j] = (short)f2bf(wv[j]);
                }
            }
    }

    // staging helpers (v regs transient)
    const int pl  = lane & 1;
    const int px0 = lane & ~1;
    auto issue_x = [&](int tile, float2* v) {
        const int wq = tile & 15;
        const float* xpx = x + (size_t)b * 4194304 + (size_t)(hq * 8) * 128 + wq * 8
                             + (px0 >> 3) * 128 + (px0 & 7);
#pragma unroll
        for (int g = 0; g < 4; ++g)
#pragma unroll
            for (int j = 0; j < 4; ++j) {
                int c = (g * 8 + wave) * 8 + 2 * j + pl;
                v[g * 4 + j] = *reinterpret_cast<const float2*>(xpx + (size_t)c * 16384);
            }
    };
    auto write_x = [&](int buf, const float2* v) {
        const int p = lane;
        unsigned char* base = s_x[buf];
#pragma unroll
        for (int g = 0; g < 4; ++g) {
            uint4 pk;
            unsigned int* pku = &pk.x;
#pragma unroll
            for (int j = 0; j < 4; ++j) {
                float2 w2 = v[g * 4 + j];
                float sel   = pl ? w2.x : w2.y;
                float other = __shfl_xor(sel, 1);
                pku[j] = pl ? pk2bf(other, w2.y) : pk2bf(w2.x, other);
            }
            int c8 = g * 8 + wave;
            *reinterpret_cast<uint4*>(base + p * 512 + ((c8 * 16) ^ ((p & 7) << 4))) = pk;
        }
    };

    {
        float2 v0[16];
        issue_x(tile0, v0);
        write_x(0, v0);
    }
    __syncthreads();

#pragma unroll 1
    for (int ti = 0; ti < 8; ++ti) {
        const int tile = tile0 + ti;
        const int wq   = wq0 + ti;
        const unsigned char* xl = s_x[ti & 1];

        // ---- GEMM: pure LDS + MFMA (W from regs). K -> acc[0..1], V -> acc[2..3] ----
        f32x4 acc[4][4];
#pragma unroll
        for (int mt = 0; mt < 4; ++mt)
#pragma unroll
            for (int nt = 0; nt < 4; ++nt) acc[mt][nt] = (f32x4){0.f, 0.f, 0.f, 0.f};
        f32x4 accQ[2];
        if (!PRE) {
#pragma unroll
            for (int mt = 0; mt < 2; ++mt) accQ[mt] = (f32x4){0.f, 0.f, 0.f, 0.f};
        }

#pragma unroll
        for (int ks = 0; ks < 8; ++ks) {
            short8 bfr[4];
#pragma unroll
            for (int nt = 0; nt < 4; ++nt) {
                int n  = nt * 16 + l15;
                int kb = ks * 32 + l4 * 8;
                bfr[nt] = *reinterpret_cast<const short8*>(
                    xl + n * 512 + ((2 * kb) ^ ((n & 7) << 4)));
            }
#pragma unroll
            for (int mt = 0; mt < 2; ++mt)
#pragma unroll
                for (int nt = 0; nt < 4; ++nt) {
                    acc[mt][nt]     = __builtin_amdgcn_mfma_f32_16x16x32_bf16(wK[mt][ks], bfr[nt], acc[mt][nt], 0, 0, 0);
                    acc[2 + mt][nt] = __builtin_amdgcn_mfma_f32_16x16x32_bf16(wV[mt][ks], bfr[nt], acc[2 + mt][nt], 0, 0, 0);
                }
            if (!PRE) {
                short8 afq[2];
#pragma unroll
                for (int mt = 0; mt < 2; ++mt) {
                    const float* wq2 = proj_w + ((wave * 2 + mt) * 16 + l15) * 256 + ks * 32 + l4 * 8;
#pragma unroll
                    for (int j = 0; j < 8; ++j) afq[mt][j] = (short)f2bf(wq2[j]);
                    accQ[mt] = __builtin_amdgcn_mfma_f32_16x16x32_bf16(afq[mt], bfr[0], accQ[mt], 0, 0, 0);
                }
            }
        }

        if (!PRE) {
            if (l15 == 0) {
#pragma unroll
                for (int mt = 0; mt < 2; ++mt)
#pragma unroll
                    for (int i = 0; i < 4; ++i) {
                        int row = wave * 32 + mt * 16 + l4 * 4 + i;
                        s_qs[row] = SCALE * (accQ[mt][i] + proj_b[row]);
                    }
            }
        }

        // ---- q/pos prefetch for THIS tile (L2-hot) — issued BEFORE staging loads ----
        float qf[2][4];
        short4v pos4[4][2];
        if (PRE) {
            const float* qp = q_all + (size_t)tile * 256 + wave * 32 + l4 * 4;
#pragma unroll
            for (int mt = 0; mt < 2; ++mt) {
                float4 qv = *reinterpret_cast<const float4*>(qp + mt * 16);
                qf[mt][0] = qv.x; qf[mt][1] = qv.y; qf[mt][2] = qv.z; qf[mt][3] = qv.w;
            }
#pragma unroll
            for (int nt = 0; nt < 4; ++nt)
#pragma unroll
                for (int mt = 0; mt < 2; ++mt)
                    pos4[nt][mt] = *reinterpret_cast<const short4v*>(
                        posT + (size_t)(nt * 16 + l15) * 256 + wave * 32 + mt * 16 + l4 * 4);
        }

        // ---- issue staging loads for next tile (drained after attention) ----
        float2 v[16];
        if (ti < 7) issue_x(tile + 1, v);

        if (!PRE) {
#pragma unroll
            for (int mt = 0; mt < 2; ++mt)
#pragma unroll
                for (int i = 0; i < 4; ++i) qf[mt][i] = s_qs[wave * 32 + mt * 16 + l4 * 4 + i];
        }

        // ---- attention: fully in-register; keys = acc[0..1] fp32 ----
        float attnw[4];
        {
            float lg[4];
#pragma unroll
            for (int nt = 0; nt < 4; ++nt) {
                float p = 0.f;
#pragma unroll
                for (int mt = 0; mt < 2; ++mt)
#pragma unroll
                    for (int i = 0; i < 4; ++i) {
                        float pf = PRE ? bf2f((unsigned short)pos4[nt][mt][i])
                                       : pos[(size_t)(wave * 32 + mt * 16 + l4 * 4 + i) * 64 + nt * 16 + l15];
                        p = fmaf(qf[mt][i], fmaf(SCALE, acc[mt][nt][i], pf), p);
                    }
                p += __shfl_xor(p, 16);   // sum the 4 l4 d-groups
                p += __shfl_xor(p, 32);
                lg[nt] = p;
            }
            float mx = fmaxf(fmaxf(lg[0], lg[1]), fmaxf(lg[2], lg[3]));
            mx = fmaxf(mx, __shfl_xor(mx, 1));
            mx = fmaxf(mx, __shfl_xor(mx, 2));
            mx = fmaxf(mx, __shfl_xor(mx, 4));
            mx = fmaxf(mx, __shfl_xor(mx, 8));
            float e0 = __expf(lg[0] - mx), e1 = __expf(lg[1] - mx);
            float e2 = __expf(lg[2] - mx), e3 = __expf(lg[3] - mx);
            float s = (e0 + e1) + (e2 + e3);
            s += __shfl_xor(s, 1);
            s += __shfl_xor(s, 2);
            s += __shfl_xor(s, 4);
            s += __shfl_xor(s, 8);
            float rs = 1.f / s;
            attnw[0] = e0 * rs; attnw[1] = e1 * rs; attnw[2] = e2 * rs; attnw[3] = e3 * rs;
        }

        // ---- epilogue: out = attn @ V from acc[2..3]; Σattn=1 folds value bias ----
#pragma unroll
        for (int mt = 0; mt < 2; ++mt) {
#pragma unroll
            for (int i = 0; i < 4; ++i) {
                float sum = attnw[0] * acc[2 + mt][0][i] + attnw[1] * acc[2 + mt][1][i]
                          + attnw[2] * acc[2 + mt][2][i] + attnw[3] * acc[2 + mt][3][i];
                sum += __shfl_xor(sum, 1);
                sum += __shfl_xor(sum, 2);
                sum += __shfl_xor(sum, 4);
                sum += __shfl_xor(sum, 8);
                if (l15 == 0) {
                    int vr = wave * 32 + mt * 16 + l4 * 4 + i;
                    out[(size_t)b * 65536 + (size_t)vr * 256 + hq * 16 + wq] = sum + s_vbias[vr];
                }
            }
        }

        // ---- publish next tile's x (drains staging loads); one barrier per tile ----
        if (ti < 7) write_x((ti & 1) ^ 1, v);
        __syncthreads();
    }
}

extern "C" void kernel_launch(void* const* d_in, const int* in_sizes, int n_in,
                              void* d_out, int out_size, void* d_ws, size_t ws_size,
                              hipStream_t stream) {
    (void)in_sizes; (void)n_in; (void)out_size;
    const float* x      = (const float*)d_in[0];
    const float* proj_w = (const float*)d_in[1];
    const float* proj_b = (const float*)d_in[2];
    const float* pos    = (const float*)d_in[3];
    float* out = (float*)d_out;

    const size_t OFF_POST = 393216;
    const size_t OFF_WQT  = 425984;
    const size_t OFF_QALL = 688128;
    const size_t need_ws  = OFF_QALL + 2097152;   // ~2.72 MB

    if (d_ws != nullptr && ws_size >= need_ws) {
        unsigned short* wp  = (unsigned short*)d_ws;
        unsigned short* pT  = (unsigned short*)((char*)d_ws + OFF_POST);
        float*          wqT = (float*)((char*)d_ws + OFF_WQT);
        float*          qA  = (float*)((char*)d_ws + OFF_QALL);
        prepack_w<<<416, 256, 0, stream>>>(proj_w, pos, wp, pT, wqT);
        q_kernel<<<512, 256, 0, stream>>>(x, wqT, proj_b, qA);
        attn_fused<true><<<256, 512, 0, stream>>>(x, proj_w, proj_b, pos, wp, pT, qA, out);
    } else {
        attn_fused<false><<<256, 512, 0, stream>>>(x, proj_w, proj_b, pos, nullptr, nullptr, nullptr, out);
    }
}

// Round 11
// 97.231 us; speedup vs baseline: 2.3688x; 2.3688x over previous
//
#include <hip/hip_runtime.h>
#include <hip/hip_bf16.h>
#include <cstdint>
#include <cstddef>

#define SCALE 0.42044820762685725f  // 32^(-1/4)

typedef __attribute__((ext_vector_type(8))) short short8;
typedef __attribute__((ext_vector_type(4))) short short4v;
typedef __attribute__((ext_vector_type(4))) float f32x4;

__device__ __forceinline__ unsigned int pk2bf(float lo, float hi) {
    __hip_bfloat162 h = __float22bfloat162_rn(float2{lo, hi});  // v_cvt_pk_bf16_f32
    unsigned int u;
    __builtin_memcpy(&u, &h, sizeof(u));
    return u;
}
__device__ __forceinline__ unsigned short f2bf(float f) {
    unsigned int u = __builtin_bit_cast(unsigned int, f);
    u = (u + 0x7fffu + ((u >> 16) & 1u)) >> 16;   // RNE
    return (unsigned short)u;
}
__device__ __forceinline__ float bf2f(unsigned short h) {
    unsigned int u = ((unsigned int)h) << 16;
    return __builtin_bit_cast(float, u);
}

// ---------------- ws layout ----------------
// [0,      393216) : W A-frags bf16 (mtg 0..15 K rows 256+16m; 16..31 V rows 512+16m; 32..47 Q rows m*16 — Q frags unused by PRE path)
// [393216, 425984) : posT bf16 [k=64][m=256]
// [425984, 688128) : WqT fp32 [c=256][o=256]
// [688128, 2785280): q_all fp32 [tile=2048][o=256] = scale*(Wq@X0 + bq)

__global__ __launch_bounds__(256) void prepack_w(const float* __restrict__ w,
                                                 const float* __restrict__ pos,
                                                 unsigned short* __restrict__ wp,
                                                 unsigned short* __restrict__ pT,
                                                 float* __restrict__ wqT) {
    int gid = blockIdx.x * 256 + threadIdx.x;    // < 106496
    if (gid < 24576) {
        int lane = gid & 63;
        int ks   = (gid >> 6) & 7;
        int mtg  = gid >> 9;                     // 0..47
        int row  = (mtg < 32 ? 256 + mtg * 16 : (mtg - 32) * 16) + (lane & 15);
        int k0   = ks * 32 + (lane >> 4) * 8;
        const float* src = w + row * 256 + k0;
        short8 v;
#pragma unroll
        for (int j = 0; j < 8; ++j) v[j] = (short)f2bf(src[j]);
        *reinterpret_cast<short8*>(wp + (size_t)gid * 8) = v;
    } else if (gid < 40960) {
        int u = gid - 24576;                     // k*256 + m
        pT[u] = f2bf(pos[(u & 255) * 64 + (u >> 8)]);
    } else {
        int u = gid - 40960;                     // c*256 + o, < 65536
        wqT[u] = w[(u & 255) * 256 + (u >> 8)];
    }
}

// ---------------- q kernel: q_all[tile][o] = scale*(Wq[o]·x[:,p0(tile)] + bq[o]) ----------------
__global__ __launch_bounds__(256) void q_kernel(const float* __restrict__ x,
                                                const float* __restrict__ wqT,
                                                const float* __restrict__ proj_b,
                                                float* __restrict__ q_all) {
    __shared__ float s_x0[4][256];
    const int t = threadIdx.x;
    const int tile0 = blockIdx.x * 4;            // 4 tiles share (b,hq)
    const int b = tile0 >> 8, hq = (tile0 >> 4) & 15, wq0 = tile0 & 15;
    {
        const float* src = x + (size_t)b * 4194304 + (size_t)t * 16384 + hq * 1024 + wq0 * 8;
#pragma unroll
        for (int j = 0; j < 4; ++j) s_x0[j][t] = src[j * 8];
    }
    __syncthreads();
    float acc[4] = {0.f, 0.f, 0.f, 0.f};
#pragma unroll 8
    for (int c = 0; c < 256; ++c) {
        float wv = wqT[c * 256 + t];             // coalesced; LDS reads broadcast
#pragma unroll
        for (int j = 0; j < 4; ++j) acc[j] = fmaf(wv, s_x0[j][c], acc[j]);
    }
    float bq = proj_b[t];
#pragma unroll
    for (int j = 0; j < 4; ++j)
        q_all[(size_t)(tile0 + j) * 256 + t] = SCALE * (acc[j] + bq);
}

// ---------------- main fused kernel: 2 WGs per tile (4 heads each), 8 waves ----------------
// Wave w<4: K for head half*4+w (acc 32 regs) -> in-register softmax -> s_attn.
// Wave w>=4: V for head half*4+(w-4) -> epilogue with s_attn weights.
// Halved per-wave state => ~5-6 waves/SIMD occupancy. 2 barriers.
template <bool PRE>
__global__ __launch_bounds__(512, 5) void attn_fused(
        const float* __restrict__ x, const float* __restrict__ proj_w,
        const float* __restrict__ proj_b, const float* __restrict__ pos,
        const unsigned short* __restrict__ wpack, const unsigned short* __restrict__ posT,
        const float* __restrict__ q_all, float* __restrict__ out) {
    __shared__ __align__(16) unsigned char s_main[32768];  // x-tile bf16 [p=64][c=256] swizzled
    __shared__ __align__(16) float s_vbias[256];
    __shared__ __align__(16) float s_attn[4][64];          // [head&3][key]
    __shared__ __align__(16) float s_qs[256];              // !PRE only

    const int t    = threadIdx.x;
    const int lane = t & 63;
    const int wave = t >> 6;
    const int l15  = lane & 15;
    const int l4   = lane >> 4;

    // Swizzle: XCD x owns image b=x; the 2 half-WGs of a tile are 8 bids apart -> same XCD.
    const int bid  = blockIdx.x;                 // < 4096
    const int xcd  = bid & 7;
    const int idx  = bid >> 3;                   // 0..511
    const int tin  = idx >> 1;                   // tile-in-image 0..255
    const int half = idx & 1;
    const int b  = xcd;
    const int hq = tin >> 4;
    const int wq = tin & 15;
    const int tile = xcd * 256 + tin;

    const int head = half * 4 + (wave & 3);      // this wave's head
    const bool isK = wave < 4;

    if (t < 256) s_vbias[t] = proj_b[512 + t];

    // ---- stage x tile -> bf16 [p][c] swizzled LDS (burst loads; 2nd WG of pair L2-hits) ----
    {
        const int p   = lane;
        const int pl  = lane & 1;
        const int px0 = lane & ~1;
        const float* xpx = x + (size_t)b * 4194304 + (size_t)(hq * 8) * 128 + wq * 8
                             + (px0 >> 3) * 128 + (px0 & 7);
        float2 v[16];
#pragma unroll
        for (int g = 0; g < 4; ++g)
#pragma unroll
            for (int j = 0; j < 4; ++j) {
                int c = (g * 8 + wave) * 8 + 2 * j + pl;
                v[g * 4 + j] = *reinterpret_cast<const float2*>(xpx + (size_t)c * 16384);
            }
#pragma unroll
        for (int g = 0; g < 4; ++g) {
            uint4 pk;
            unsigned int* pku = &pk.x;
#pragma unroll
            for (int j = 0; j < 4; ++j) {
                float2 w2 = v[g * 4 + j];
                float sel   = pl ? w2.x : w2.y;
                float other = __shfl_xor(sel, 1);
                pku[j] = pl ? pk2bf(other, w2.y) : pk2bf(w2.x, other);
            }
            int c8 = g * 8 + wave;
            *reinterpret_cast<uint4*>(s_main + p * 512 + ((c8 * 16) ^ ((p & 7) << 4))) = pk;
        }
    }
    __syncthreads();   // barrier 1

    // ---- GEMM: this wave's K (rows 256+32h..) or V (rows 512+32h..) -> acc[2][4] ----
    f32x4 acc[2][4];
#pragma unroll
    for (int mt = 0; mt < 2; ++mt)
#pragma unroll
        for (int nt = 0; nt < 4; ++nt) acc[mt][nt] = (f32x4){0.f, 0.f, 0.f, 0.f};
    f32x4 accQ[2];
    if (!PRE && isK) {
#pragma unroll
        for (int mt = 0; mt < 2; ++mt) accQ[mt] = (f32x4){0.f, 0.f, 0.f, 0.f};
    }

    const int mtg0 = (isK ? 0 : 16) + head * 2;

#pragma unroll 2
    for (int ks = 0; ks < 8; ++ks) {
        short8 bfr[4];
#pragma unroll
        for (int nt = 0; nt < 4; ++nt) {
            int n  = nt * 16 + l15;
            int kb = ks * 32 + l4 * 8;
            bfr[nt] = *reinterpret_cast<const short8*>(
                s_main + n * 512 + ((2 * kb) ^ ((n & 7) << 4)));
        }
        short8 af[2];
#pragma unroll
        for (int mt = 0; mt < 2; ++mt) {
            if (PRE) {
                af[mt] = *reinterpret_cast<const short8*>(
                    wpack + ((size_t)(((mtg0 + mt) * 8 + ks) * 64 + lane)) * 8);
            } else {
                int row = (isK ? 256 : 512) + head * 32 + mt * 16 + l15;
                const float* src = proj_w + row * 256 + ks * 32 + l4 * 8;
#pragma unroll
                for (int j = 0; j < 8; ++j) af[mt][j] = (short)f2bf(src[j]);
            }
        }
#pragma unroll
        for (int mt = 0; mt < 2; ++mt)
#pragma unroll
            for (int nt = 0; nt < 4; ++nt)
                acc[mt][nt] = __builtin_amdgcn_mfma_f32_16x16x32_bf16(af[mt], bfr[nt], acc[mt][nt], 0, 0, 0);
        if (!PRE && isK) {
            short8 afq[2];
#pragma unroll
            for (int mt = 0; mt < 2; ++mt) {
                const float* wq2 = proj_w + (head * 32 + mt * 16 + l15) * 256 + ks * 32 + l4 * 8;
#pragma unroll
                for (int j = 0; j < 8; ++j) afq[mt][j] = (short)f2bf(wq2[j]);
                accQ[mt] = __builtin_amdgcn_mfma_f32_16x16x32_bf16(afq[mt], bfr[0], accQ[mt], 0, 0, 0);
            }
        }
    }

    // ---- K-waves: in-register softmax for own head -> publish attn weights ----
    if (isK) {
        if (!PRE) {
            if (l15 == 0) {
#pragma unroll
                for (int mt = 0; mt < 2; ++mt)
#pragma unroll
                    for (int i = 0; i < 4; ++i) {
                        int row = head * 32 + mt * 16 + l4 * 4 + i;
                        s_qs[row] = SCALE * (accQ[mt][i] + proj_b[row]);
                    }
            }
        }
        float qf[2][4];
        short4v pos4[4][2];
        if (PRE) {
            const float* qp = q_all + (size_t)tile * 256 + head * 32 + l4 * 4;
#pragma unroll
            for (int mt = 0; mt < 2; ++mt) {
                float4 qv = *reinterpret_cast<const float4*>(qp + mt * 16);
                qf[mt][0] = qv.x; qf[mt][1] = qv.y; qf[mt][2] = qv.z; qf[mt][3] = qv.w;
            }
#pragma unroll
            for (int nt = 0; nt < 4; ++nt)
#pragma unroll
                for (int mt = 0; mt < 2; ++mt)
                    pos4[nt][mt] = *reinterpret_cast<const short4v*>(
                        posT + (size_t)(nt * 16 + l15) * 256 + head * 32 + mt * 16 + l4 * 4);
        } else {
#pragma unroll
            for (int mt = 0; mt < 2; ++mt)
#pragma unroll
                for (int i = 0; i < 4; ++i) qf[mt][i] = s_qs[head * 32 + mt * 16 + l4 * 4 + i];
        }

        float lg[4];
#pragma unroll
        for (int nt = 0; nt < 4; ++nt) {
            float p = 0.f;
#pragma unroll
            for (int mt = 0; mt < 2; ++mt)
#pragma unroll
                for (int i = 0; i < 4; ++i) {
                    float pf = PRE ? bf2f((unsigned short)pos4[nt][mt][i])
                                   : pos[(size_t)(head * 32 + mt * 16 + l4 * 4 + i) * 64 + nt * 16 + l15];
                    p = fmaf(qf[mt][i], fmaf(SCALE, acc[mt][nt][i], pf), p);
                }
            p += __shfl_xor(p, 16);   // sum the 4 l4 d-groups
            p += __shfl_xor(p, 32);
            lg[nt] = p;
        }
        float mx = fmaxf(fmaxf(lg[0], lg[1]), fmaxf(lg[2], lg[3]));
        mx = fmaxf(mx, __shfl_xor(mx, 1));
        mx = fmaxf(mx, __shfl_xor(mx, 2));
        mx = fmaxf(mx, __shfl_xor(mx, 4));
        mx = fmaxf(mx, __shfl_xor(mx, 8));
        float e0 = __expf(lg[0] - mx), e1 = __expf(lg[1] - mx);
        float e2 = __expf(lg[2] - mx), e3 = __expf(lg[3] - mx);
        float s = (e0 + e1) + (e2 + e3);
        s += __shfl_xor(s, 1);
        s += __shfl_xor(s, 2);
        s += __shfl_xor(s, 4);
        s += __shfl_xor(s, 8);
        float rs = 1.f / s;
        if (l4 == 0) {
            s_attn[head & 3][l15]      = e0 * rs;
            s_attn[head & 3][16 + l15] = e1 * rs;
            s_attn[head & 3][32 + l15] = e2 * rs;
            s_attn[head & 3][48 + l15] = e3 * rs;
        }
    }
    __syncthreads();   // barrier 2: attn weights visible

    // ---- V-waves: epilogue out = attn @ V; Σattn=1 folds value bias ----
    if (!isK) {
        const float* ap = s_attn[head & 3];
        float a0 = ap[l15], a1 = ap[16 + l15], a2 = ap[32 + l15], a3 = ap[48 + l15];
#pragma unroll
        for (int mt = 0; mt < 2; ++mt) {
#pragma unroll
            for (int i = 0; i < 4; ++i) {
                float sum = a0 * acc[mt][0][i] + a1 * acc[mt][1][i]
                          + a2 * acc[mt][2][i] + a3 * acc[mt][3][i];
                sum += __shfl_xor(sum, 1);
                sum += __shfl_xor(sum, 2);
                sum += __shfl_xor(sum, 4);
                sum += __shfl_xor(sum, 8);
                if (l15 == 0) {
                    int vr = head * 32 + mt * 16 + l4 * 4 + i;
                    out[(size_t)b * 65536 + (size_t)vr * 256 + hq * 16 + wq] = sum + s_vbias[vr];
                }
            }
        }
    }
}

extern "C" void kernel_launch(void* const* d_in, const int* in_sizes, int n_in,
                              void* d_out, int out_size, void* d_ws, size_t ws_size,
                              hipStream_t stream) {
    (void)in_sizes; (void)n_in; (void)out_size;
    const float* x      = (const float*)d_in[0];
    const float* proj_w = (const float*)d_in[1];
    const float* proj_b = (const float*)d_in[2];
    const float* pos    = (const float*)d_in[3];
    float* out = (float*)d_out;

    const size_t OFF_POST = 393216;
    const size_t OFF_WQT  = 425984;
    const size_t OFF_QALL = 688128;
    const size_t need_ws  = OFF_QALL + 2097152;   // ~2.72 MB

    if (d_ws != nullptr && ws_size >= need_ws) {
        unsigned short* wp  = (unsigned short*)d_ws;
        unsigned short* pT  = (unsigned short*)((char*)d_ws + OFF_POST);
        float*          wqT = (float*)((char*)d_ws + OFF_WQT);
        float*          qA  = (float*)((char*)d_ws + OFF_QALL);
        prepack_w<<<416, 256, 0, stream>>>(proj_w, pos, wp, pT, wqT);
        q_kernel<<<512, 256, 0, stream>>>(x, wqT, proj_b, qA);
        attn_fused<true><<<4096, 512, 0, stream>>>(x, proj_w, proj_b, pos, wp, pT, qA, out);
    } else {
        attn_fused<false><<<4096, 512, 0, stream>>>(x, proj_w, proj_b, pos, nullptr, nullptr, nullptr, out);
    }
}